// Round 2
// baseline (713.598 us; speedup 1.0000x reference)
//
#include <hip/hip_runtime.h>
#include <hip/hip_bf16.h>

// AttnDecoderRNN. B=128, S=400, H=256, E=128, V=50000, PAD=250.
// 4 dispatches, all full-chip parallel:
//   D1 k_gates        : gi/gh MFMA GEMMs + zero counters/row sums
//   D2 k_attn         : chunked attention partials (grid 8 x 128); the LAST
//                       chunk-block per row (atomic counter + threadfence)
//                       finalizes softmax, context, outh GEMV, p_gen
//   D3 k_vocab_mfma   : vocab GEMM -> exp + striped row sums
//   D4 k_final_scatter: normalize chunks (grid 25 x 128); LAST chunk-block
//                       per row does the scatter atomics

#define B_ 128
#define S_ 400
#define H_ 256
#define E_ 128
#define V_ 50000
#define PAD_ 250
#define VP_ (V_ + PAD_)
#define NC_ 8            // attention S-chunks
#define CS_ (S_ / NC_)   // 50
#define NSUM_ 16         // striped row_sum copies
#define GF_ 25           // final-normalize chunks (25*2048 >= VP_)

typedef unsigned short ushort_t;
typedef __attribute__((ext_vector_type(8))) short bf16x8;
typedef __attribute__((ext_vector_type(4))) float f32x4;

__device__ __forceinline__ unsigned short f2bfu(float f) {
    __hip_bfloat16 h = __float2bfloat16(f);  // RNE
    union { __hip_bfloat16 h; unsigned short u; } c;
    c.h = h;
    return c.u;
}

__device__ __forceinline__ float sigmoid_fast(float x) {
    return 1.0f / (1.0f + __expf(-x));
}

__device__ __forceinline__ float tanh_fast(float x) {
    return 1.0f - 2.0f / (__expf(2.0f * x) + 1.0f);
}

__device__ __forceinline__ float waveReduceSumAll(float v) {
#pragma unroll
    for (int off = 1; off < 64; off <<= 1) v += __shfl_xor(v, off, 64);
    return v;
}

// ---------- D1: GRU gates GEMM via MFMA + workspace zeroing ----------
// Blocks 0..11: IH tiles (stage x only, pitch 136). Blocks 12..23: HH (h only, pitch 264).
__global__ __launch_bounds__(256) void k_gates(
    const int* __restrict__ token, const float* __restrict__ emb,
    const float* __restrict__ hprev,
    const float* __restrict__ w_ih, const float* __restrict__ w_hh,
    float* __restrict__ gi_ws, float* __restrict__ gh_ws,
    float* __restrict__ row_sum16, int* __restrict__ cnt_attn, int* __restrict__ cnt_fin) {
    __shared__ ushort_t xh[B_ * 264];   // 67584 B (max of both layouts)
    __shared__ int toks[B_];
    int t = threadIdx.x;
    bool isIH = blockIdx.x < 12;
    if (blockIdx.x == 0) {
        for (int i = t; i < NSUM_ * B_; i += 256) row_sum16[i] = 0.0f;
        if (t < B_) { cnt_attn[t] = 0; cnt_fin[t] = 0; }
    }
    if (isIH) {
        if (t < B_) toks[t] = token[t];
        __syncthreads();
#pragma unroll
        for (int i = 0; i < 16; i++) {            // x gather: 128 x 32 float4
            int fidx = i * 256 + t;
            int b = fidx >> 5, k4 = fidx & 31;
            float4 q = *(const float4*)(emb + (size_t)toks[b] * E_ + k4 * 4);
            ushort4 u;
            u.x = f2bfu(q.x); u.y = f2bfu(q.y); u.z = f2bfu(q.z); u.w = f2bfu(q.w);
            *(ushort4*)&xh[b * 136 + k4 * 4] = u;
        }
    } else {
#pragma unroll
        for (int i = 0; i < 32; i++) {            // h: 128 x 64 float4
            int fidx = i * 256 + t;
            int b = fidx >> 6, k4 = fidx & 63;
            float4 q = *(const float4*)(hprev + (size_t)b * H_ + k4 * 4);
            ushort4 u;
            u.x = f2bfu(q.x); u.y = f2bfu(q.y); u.z = f2bfu(q.z); u.w = f2bfu(q.w);
            *(ushort4*)&xh[b * 264 + k4 * 4] = u;
        }
    }
    __syncthreads();

    int wave = t >> 6, lane = t & 63, lm = lane & 15, quad = lane >> 4;
    int tile = (isIH ? blockIdx.x : blockIdx.x - 12) * 4 + wave;   // 0..47
    int v = tile * 16 + lm;
    int K = isIH ? E_ : H_;
    int pitch = isIH ? 136 : 264;
    const float* wrow = (isIH ? w_ih : w_hh) + (size_t)v * K;
    float* gout = isIH ? gi_ws : gh_ws;

    f32x4 acc[8];
#pragma unroll
    for (int bt = 0; bt < 8; bt++) acc[bt] = (f32x4){0.f, 0.f, 0.f, 0.f};

    for (int kc = 0; kc < (K >> 5); kc++) {
        int k0 = kc * 32 + quad * 8;
        float4 w0 = *(const float4*)(wrow + k0);
        float4 w1 = *(const float4*)(wrow + k0 + 4);
        bf16x8 bf;
        bf[0] = (short)f2bfu(w0.x); bf[1] = (short)f2bfu(w0.y);
        bf[2] = (short)f2bfu(w0.z); bf[3] = (short)f2bfu(w0.w);
        bf[4] = (short)f2bfu(w1.x); bf[5] = (short)f2bfu(w1.y);
        bf[6] = (short)f2bfu(w1.z); bf[7] = (short)f2bfu(w1.w);
#pragma unroll
        for (int bt = 0; bt < 8; bt++) {
            bf16x8 af = *(const bf16x8*)&xh[(bt * 16 + lm) * pitch + k0];
            acc[bt] = __builtin_amdgcn_mfma_f32_16x16x32_bf16(af, bf, acc[bt], 0, 0, 0);
        }
    }
#pragma unroll
    for (int bt = 0; bt < 8; bt++)
#pragma unroll
        for (int r = 0; r < 4; r++) {
            int b = bt * 16 + quad * 4 + r;
            gout[(size_t)b * 768 + v] = acc[bt][r];
        }
}

// ---------- D2: chunked attention + last-block combine ----------
// Grid (NC_, B_) x 256. GRU-nl recomputed per block (cheap); block c==0 writes h_new.
__global__ __launch_bounds__(256) void k_attn(
    const float* __restrict__ gi_ws, const float* __restrict__ gh_ws,
    const float* __restrict__ b_ih, const float* __restrict__ b_hh,
    const float* __restrict__ hprev,
    const float* __restrict__ enc,
    const float* __restrict__ w_h, const float* __restrict__ w_s,
    const float* __restrict__ att_bias, const float* __restrict__ attn_v,
    const int* __restrict__ token, const float* __restrict__ emb,
    const float* __restrict__ outh_w, const float* __restrict__ outh_b,
    const float* __restrict__ gen_w, const float* __restrict__ gen_b,
    float* __restrict__ out_hnew, float* __restrict__ out_attd,
    float* __restrict__ out_pgen,
    float* __restrict__ sc_ws, float* __restrict__ ml_ws, float* __restrict__ ctxp_ws,
    float* __restrict__ hidden_ws, int* __restrict__ cnt_attn) {
    int c = blockIdx.x, b = blockIdx.y;
    int t = threadIdx.x;
    int wave = t >> 6, lane = t & 63;
    __shared__ float whs[H_], vs[H_], cs[H_], cmerge[H_], hs[H_];
    __shared__ float mred[4], lred[4], r2[4];
    __shared__ float dc[2 * H_ + E_];
    __shared__ float ml[NC_ * 2];
    __shared__ int lastflag;

    // GRU nonlinearity for this b (t = h index)
    {
        float ir = gi_ws[(size_t)b * 768 + t] + b_ih[t];
        float iz = gi_ws[(size_t)b * 768 + 256 + t] + b_ih[256 + t];
        float in_ = gi_ws[(size_t)b * 768 + 512 + t] + b_ih[512 + t];
        float hr = gh_ws[(size_t)b * 768 + t] + b_hh[t];
        float hz = gh_ws[(size_t)b * 768 + 256 + t] + b_hh[256 + t];
        float hn = gh_ws[(size_t)b * 768 + 512 + t] + b_hh[512 + t];
        float hp = hprev[(size_t)b * H_ + t];
        float r = sigmoid_fast(ir + hr);
        float z = sigmoid_fast(iz + hz);
        float n = tanh_fast(in_ + r * hn);
        float h = (1.0f - z) * n + z * hp;
        if (c == 0) out_hnew[(size_t)b * H_ + t] = h;
        hs[t] = h;
        whs[t] = w_h[t];
        vs[t] = attn_v[t];
        cs[t] = w_s[t] * h + att_bias[0];
        cmerge[t] = 0.0f;
    }
    __syncthreads();

    int h0 = lane * 4;
    float m_w = -1e30f, l_w = 0.0f;
    float cx0 = 0.f, cx1 = 0.f, cx2 = 0.f, cx3 = 0.f;
    for (int si = wave; si < CS_; si += 4) {
        int s = c * CS_ + si;
        float4 u = *(const float4*)(enc + ((size_t)(b * S_ + s)) * H_ + h0);
        float p = vs[h0 + 0] * tanh_fast(whs[h0 + 0] * u.x + cs[h0 + 0])
                + vs[h0 + 1] * tanh_fast(whs[h0 + 1] * u.y + cs[h0 + 1])
                + vs[h0 + 2] * tanh_fast(whs[h0 + 2] * u.z + cs[h0 + 2])
                + vs[h0 + 3] * tanh_fast(whs[h0 + 3] * u.w + cs[h0 + 3]);
        p = waveReduceSumAll(p);
        if (lane == 0) sc_ws[b * S_ + s] = p;
        float mn = fmaxf(m_w, p);
        float scale = __expf(m_w - mn);
        float w = __expf(p - mn);
        cx0 = cx0 * scale + w * u.x;
        cx1 = cx1 * scale + w * u.y;
        cx2 = cx2 * scale + w * u.z;
        cx3 = cx3 * scale + w * u.w;
        l_w = l_w * scale + w;
        m_w = mn;
    }
    if (lane == 0) mred[wave] = m_w;
    __syncthreads();
    float m_c = fmaxf(fmaxf(mred[0], mred[1]), fmaxf(mred[2], mred[3]));
    float wf = __expf(m_w - m_c);
    if (lane == 0) lred[wave] = l_w * wf;
    atomicAdd(&cmerge[h0 + 0], cx0 * wf);
    atomicAdd(&cmerge[h0 + 1], cx1 * wf);
    atomicAdd(&cmerge[h0 + 2], cx2 * wf);
    atomicAdd(&cmerge[h0 + 3], cx3 * wf);
    __syncthreads();
    if (t == 0) {
        ml_ws[(b * NC_ + c) * 2 + 0] = m_c;
        ml_ws[(b * NC_ + c) * 2 + 1] = lred[0] + lred[1] + lred[2] + lred[3];
    }
    ctxp_ws[(size_t)(b * NC_ + c) * H_ + t] = cmerge[t];

    // ---- decoupled handoff: last block for this row does the combine ----
    __threadfence();                       // release our partials (all threads)
    __syncthreads();
    if (t == 0) lastflag = (atomicAdd(&cnt_attn[b], 1) == NC_ - 1);
    __syncthreads();
    if (!lastflag) return;
    __threadfence();                       // acquire other blocks' partials

    if (t < NC_ * 2) ml[t] = ml_ws[b * NC_ * 2 + t];
    __syncthreads();
    float M = -1e30f;
#pragma unroll
    for (int cc = 0; cc < NC_; cc++) M = fmaxf(M, ml[2 * cc]);
    float L = 0.0f;
#pragma unroll
    for (int cc = 0; cc < NC_; cc++) L += ml[2 * cc + 1] * __expf(ml[2 * cc] - M);
    float invL = 1.0f / L;

    for (int s = t; s < S_; s += 256)
        out_attd[(size_t)b * S_ + s] = __expf(sc_ws[b * S_ + s] - M) * invL;

    {
        float acc = 0.0f;
#pragma unroll
        for (int cc = 0; cc < NC_; cc++)
            acc += __expf(ml[2 * cc] - M) * ctxp_ws[(size_t)(b * NC_ + cc) * H_ + t];
        dc[t] = hs[t];
        dc[H_ + t] = acc * invL;
    }
    if (t < E_) dc[2 * H_ + t] = emb[(size_t)token[b] * E_ + t];
    __syncthreads();

    // hidden[r] = dot(outh_w[r, 0:512], dc[0:512]) + outh_b[r], 2 thr/row
    {
        int r = t >> 1, sub = t & 1;
        const float* wrow = outh_w + (size_t)r * (2 * H_);
        float acc = 0.0f;
#pragma unroll
        for (int i = 0; i < 64; i++) {
            int k = i * 8 + sub * 4;
            float4 q = *(const float4*)(wrow + k);
            acc += dc[k] * q.x + dc[k + 1] * q.y + dc[k + 2] * q.z + dc[k + 3] * q.w;
        }
        acc += __shfl_down(acc, 1, 64);
        if (sub == 0) hidden_ws[(size_t)b * E_ + r] = acc + outh_b[r];
    }
    // p_gen: dot(dc[0:640], gen_w)
    {
        float pp = dc[t] * gen_w[t] + dc[t + 256] * gen_w[t + 256]
                 + ((t < E_) ? dc[t + 512] * gen_w[t + 512] : 0.0f);
        pp = waveReduceSumAll(pp);
        if (lane == 0) r2[wave] = pp;
        __syncthreads();
        if (t == 0)
            out_pgen[b] = sigmoid_fast(r2[0] + r2[1] + r2[2] + r2[3] + gen_b[0]);
    }
}

// ---------- D3: vocab GEMM (MFMA bf16) -> exp (f32 into p_vocab) + striped row sums --
#define VT_TOTAL (V_ / 16)          // 3125
#define HID_PITCH 136               // 128+8 shorts
__global__ __launch_bounds__(256) void k_vocab_mfma(
    const float* __restrict__ outv_w, const float* __restrict__ outv_b,
    const float* __restrict__ hidden_ws,
    float* __restrict__ out_pvocab, float* __restrict__ row_sum16) {
    __shared__ ushort_t hid[B_ * HID_PITCH];   // 34816 B
    __shared__ float rsum[B_];
    int t = threadIdx.x;

    const float4* h4 = (const float4*)hidden_ws;
#pragma unroll
    for (int i = 0; i < 16; i++) {
        int fidx = i * 256 + t;
        float4 q = h4[fidx];
        int row = fidx >> 5;
        int col = (fidx & 31) << 2;
        ushort4 u;
        u.x = f2bfu(q.x); u.y = f2bfu(q.y); u.z = f2bfu(q.z); u.w = f2bfu(q.w);
        *(ushort4*)&hid[row * HID_PITCH + col] = u;
    }
    if (t < B_) rsum[t] = 0.0f;
    __syncthreads();

    int wave = t >> 6, lane = t & 63, lm = lane & 15, quad = lane >> 4;
    int vt = blockIdx.x * 4 + wave;

    if (vt < VT_TOTAL) {
        int v = vt * 16 + lm;
        const float* wrow = outv_w + (size_t)v * E_;

        f32x4 acc[8];
#pragma unroll
        for (int bt = 0; bt < 8; bt++) acc[bt] = (f32x4){0.f, 0.f, 0.f, 0.f};

#pragma unroll
        for (int kc = 0; kc < 4; kc++) {
            int k0 = kc * 32 + quad * 8;
            float4 w0 = *(const float4*)(wrow + k0);
            float4 w1 = *(const float4*)(wrow + k0 + 4);
            bf16x8 bf;
            bf[0] = (short)f2bfu(w0.x); bf[1] = (short)f2bfu(w0.y);
            bf[2] = (short)f2bfu(w0.z); bf[3] = (short)f2bfu(w0.w);
            bf[4] = (short)f2bfu(w1.x); bf[5] = (short)f2bfu(w1.y);
            bf[6] = (short)f2bfu(w1.z); bf[7] = (short)f2bfu(w1.w);
#pragma unroll
            for (int bt = 0; bt < 8; bt++) {
                bf16x8 af = *(const bf16x8*)&hid[(bt * 16 + lm) * HID_PITCH + k0];
                acc[bt] = __builtin_amdgcn_mfma_f32_16x16x32_bf16(af, bf, acc[bt], 0, 0, 0);
            }
        }

        float bias = outv_b[v];
#pragma unroll
        for (int bt = 0; bt < 8; bt++) {
#pragma unroll
            for (int r = 0; r < 4; r++) {
                int b = bt * 16 + quad * 4 + r;
                float e = __expf(fminf(acc[bt][r] + bias, 60.0f));
                out_pvocab[(size_t)b * V_ + v] = e;
                float s = e;
                s += __shfl_xor(s, 1);
                s += __shfl_xor(s, 2);
                s += __shfl_xor(s, 4);
                s += __shfl_xor(s, 8);
                if (lm == 0) atomicAdd(&rsum[b], s);
            }
        }
    }
    __syncthreads();
    if (t < B_) atomicAdd(&row_sum16[(blockIdx.x & (NSUM_ - 1)) * B_ + t], rsum[t]);
}

// ---------- D4: chunked normalize + last-block scatter ----------
// Grid (GF_, B_) x 256. Chunk g covers j in [g*2048, g*2048+2048).
__global__ __launch_bounds__(256) void k_final_scatter(
    const float* __restrict__ row_sum16, const float* __restrict__ pgen,
    const int* __restrict__ fiv, const float* __restrict__ attd,
    float* __restrict__ out_pfinal, float* __restrict__ out_pvocab,
    int* __restrict__ cnt_fin) {
    int g = blockIdx.x, b = blockIdx.y;
    int t = threadIdx.x;
    __shared__ int lastflag;
    float rs = 0.0f;
#pragma unroll
    for (int i = 0; i < NSUM_; i++) rs += row_sum16[i * B_ + b];
    float inv = 1.0f / rs;
    float pg = pgen[b];
    float omg = 1.0f - pg;
    float* pvrow = out_pvocab + (size_t)b * V_;
    float* pfrow = out_pfinal + (size_t)b * VP_;

    int j0 = g * 2048;
    // p_vocab rows are 16B-aligned; p_final rows only 8B-aligned -> float2 stores.
    for (int i4 = t; i4 < 512; i4 += 256) {
        int j = j0 + i4 * 4;
        if (j + 4 <= V_) {
            float4 p = *(float4*)(pvrow + j);
            p.x *= inv; p.y *= inv; p.z *= inv; p.w *= inv;
            *(float4*)(pvrow + j) = p;
            float2 a; a.x = p.x * pg; a.y = p.y * pg;
            float2 cc; cc.x = p.z * pg; cc.y = p.w * pg;
            *(float2*)(pfrow + j) = a;
            *(float2*)(pfrow + j + 2) = cc;
        } else {
#pragma unroll
            for (int k = 0; k < 4; k++) {
                int jj = j + k;
                if (jj < V_) {
                    float p = pvrow[jj] * inv;
                    pvrow[jj] = p;
                    pfrow[jj] = p * pg;
                } else if (jj < VP_) {
                    pfrow[jj] = 0.0f;
                }
            }
        }
    }

    // ---- decoupled handoff: last chunk-block for this row does the scatter ----
    __threadfence();                       // release our p_final stores
    __syncthreads();
    if (t == 0) lastflag = (atomicAdd(&cnt_fin[b], 1) == GF_ - 1);
    __syncthreads();
    if (!lastflag) return;
    __threadfence();

    for (int s = t; s < S_; s += 256) {
        int idx = fiv[b * S_ + s];
        atomicAdd(&pfrow[idx], omg * attd[(size_t)b * S_ + s]);
    }
}

extern "C" void kernel_launch(void* const* d_in, const int* in_sizes, int n_in,
                              void* d_out, int out_size, void* d_ws, size_t ws_size,
                              hipStream_t stream) {
    const int* token = (const int*)d_in[0];
    const float* hprev = (const float*)d_in[1];
    const float* enc = (const float*)d_in[2];
    const int* fiv = (const int*)d_in[3];
    const float* emb = (const float*)d_in[4];
    const float* w_ih = (const float*)d_in[5];
    const float* w_hh = (const float*)d_in[6];
    const float* b_ih = (const float*)d_in[7];
    const float* b_hh = (const float*)d_in[8];
    const float* w_h = (const float*)d_in[9];
    const float* w_s = (const float*)d_in[10];
    const float* att_bias = (const float*)d_in[11];
    const float* attn_v = (const float*)d_in[12];
    const float* gen_w = (const float*)d_in[13];
    const float* gen_b = (const float*)d_in[14];
    const float* outh_w = (const float*)d_in[15];
    const float* outh_b = (const float*)d_in[16];
    const float* outv_w = (const float*)d_in[17];
    const float* outv_b = (const float*)d_in[18];

    float* out = (float*)d_out;
    float* out_hnew = out;                                    // B*H
    float* out_pfinal = out + (size_t)B_ * H_;                // B*VP
    float* out_pgen = out_pfinal + (size_t)B_ * VP_;          // B
    float* out_pvocab = out_pgen + B_;                        // B*V
    float* out_attd = out_pvocab + (size_t)B_ * V_;           // B*S

    float* wsf = (float*)d_ws;
    float* gi_ws = wsf;                      // 98304 floats
    float* gh_ws = wsf + 98304;              // 98304
    float* hidden_ws = wsf + 196608;         // 16384
    float* row_sum16 = wsf + 212992;         // 2048
    float* sc_ws = wsf + 215040;             // 51200
    float* ml_ws = wsf + 266240;             // 2048
    float* ctxp_ws = wsf + 268288;           // 262144
    int* cnt_attn = (int*)(wsf + 530432);    // 128
    int* cnt_fin = (int*)(wsf + 530560);     // 128

    k_gates<<<24, 256, 0, stream>>>(token, emb, hprev, w_ih, w_hh, gi_ws, gh_ws,
                                    row_sum16, cnt_attn, cnt_fin);
    k_attn<<<dim3(NC_, B_), 256, 0, stream>>>(gi_ws, gh_ws, b_ih, b_hh, hprev,
                                              enc, w_h, w_s, att_bias, attn_v,
                                              token, emb, outh_w, outh_b, gen_w, gen_b,
                                              out_hnew, out_attd, out_pgen,
                                              sc_ws, ml_ws, ctxp_ws,
                                              hidden_ws, cnt_attn);
    k_vocab_mfma<<<782, 256, 0, stream>>>(outv_w, outv_b, hidden_ws, out_pvocab, row_sum16);
    k_final_scatter<<<dim3(GF_, B_), 256, 0, stream>>>(row_sum16, out_pgen, fiv, out_attd,
                                                       out_pfinal, out_pvocab, cnt_fin);
}

// Round 3
// 226.965 us; speedup vs baseline: 3.1441x; 3.1441x over previous
//
#include <hip/hip_runtime.h>
#include <hip/hip_bf16.h>

// AttnDecoderRNN. B=128, S=400, H=256, E=128, V=50000, PAD=250.
// 6 stream-ordered dispatches (NO device fences — threadfence-per-block
// serializes on gfx950's non-coherent per-XCD L2s; measured 423 us in R2):
//   D1 k_gates      : gi/gh MFMA GEMMs + zero row sums
//   D2 k_attn       : chunked attention partials (grid 8 x 128)
//   D3 k_combine    : softmax finalize + attd + context + outh GEMV + p_gen
//                     (stores hidden as bf16 for the vocab passes)
//   D4 k_vocab_sum  : vocab GEMM -> exp -> striped row sums (NO exp store)
//   D5 k_vocab_write: identical GEMM (outv_w L3-resident) -> exp -> write
//                     normalized p_vocab and dense p_final
//   D6 k_scatter    : zero PAD region, then scatter atomics (block-local order)

#define B_ 128
#define S_ 400
#define H_ 256
#define E_ 128
#define V_ 50000
#define PAD_ 250
#define VP_ (V_ + PAD_)
#define NC_ 8            // attention S-chunks
#define CS_ (S_ / NC_)   // 50
#define NSUM_ 16         // striped row_sum copies

typedef unsigned short ushort_t;
typedef __attribute__((ext_vector_type(8))) short bf16x8;
typedef __attribute__((ext_vector_type(4))) float f32x4;

__device__ __forceinline__ unsigned short f2bfu(float f) {
    __hip_bfloat16 h = __float2bfloat16(f);  // RNE
    union { __hip_bfloat16 h; unsigned short u; } c;
    c.h = h;
    return c.u;
}

__device__ __forceinline__ float sigmoid_fast(float x) {
    return 1.0f / (1.0f + __expf(-x));
}

__device__ __forceinline__ float tanh_fast(float x) {
    return 1.0f - 2.0f / (__expf(2.0f * x) + 1.0f);
}

__device__ __forceinline__ float waveReduceSumAll(float v) {
#pragma unroll
    for (int off = 1; off < 64; off <<= 1) v += __shfl_xor(v, off, 64);
    return v;
}

// ---------- D1: GRU gates GEMM via MFMA + row_sum zeroing ----------
// Blocks 0..11: IH tiles (stage x only, pitch 136). Blocks 12..23: HH (h only, pitch 264).
__global__ __launch_bounds__(256) void k_gates(
    const int* __restrict__ token, const float* __restrict__ emb,
    const float* __restrict__ hprev,
    const float* __restrict__ w_ih, const float* __restrict__ w_hh,
    float* __restrict__ gi_ws, float* __restrict__ gh_ws,
    float* __restrict__ row_sum16) {
    __shared__ ushort_t xh[B_ * 264];   // 67584 B (max of both layouts)
    __shared__ int toks[B_];
    int t = threadIdx.x;
    bool isIH = blockIdx.x < 12;
    if (blockIdx.x == 0) {
        for (int i = t; i < NSUM_ * B_; i += 256) row_sum16[i] = 0.0f;
    }
    if (isIH) {
        if (t < B_) toks[t] = token[t];
        __syncthreads();
#pragma unroll
        for (int i = 0; i < 16; i++) {            // x gather: 128 x 32 float4
            int fidx = i * 256 + t;
            int b = fidx >> 5, k4 = fidx & 31;
            float4 q = *(const float4*)(emb + (size_t)toks[b] * E_ + k4 * 4);
            ushort4 u;
            u.x = f2bfu(q.x); u.y = f2bfu(q.y); u.z = f2bfu(q.z); u.w = f2bfu(q.w);
            *(ushort4*)&xh[b * 136 + k4 * 4] = u;
        }
    } else {
#pragma unroll
        for (int i = 0; i < 32; i++) {            // h: 128 x 64 float4
            int fidx = i * 256 + t;
            int b = fidx >> 6, k4 = fidx & 63;
            float4 q = *(const float4*)(hprev + (size_t)b * H_ + k4 * 4);
            ushort4 u;
            u.x = f2bfu(q.x); u.y = f2bfu(q.y); u.z = f2bfu(q.z); u.w = f2bfu(q.w);
            *(ushort4*)&xh[b * 264 + k4 * 4] = u;
        }
    }
    __syncthreads();

    int wave = t >> 6, lane = t & 63, lm = lane & 15, quad = lane >> 4;
    int tile = (isIH ? blockIdx.x : blockIdx.x - 12) * 4 + wave;   // 0..47
    int v = tile * 16 + lm;
    int K = isIH ? E_ : H_;
    int pitch = isIH ? 136 : 264;
    const float* wrow = (isIH ? w_ih : w_hh) + (size_t)v * K;
    float* gout = isIH ? gi_ws : gh_ws;

    f32x4 acc[8];
#pragma unroll
    for (int bt = 0; bt < 8; bt++) acc[bt] = (f32x4){0.f, 0.f, 0.f, 0.f};

    for (int kc = 0; kc < (K >> 5); kc++) {
        int k0 = kc * 32 + quad * 8;
        float4 w0 = *(const float4*)(wrow + k0);
        float4 w1 = *(const float4*)(wrow + k0 + 4);
        bf16x8 bf;
        bf[0] = (short)f2bfu(w0.x); bf[1] = (short)f2bfu(w0.y);
        bf[2] = (short)f2bfu(w0.z); bf[3] = (short)f2bfu(w0.w);
        bf[4] = (short)f2bfu(w1.x); bf[5] = (short)f2bfu(w1.y);
        bf[6] = (short)f2bfu(w1.z); bf[7] = (short)f2bfu(w1.w);
#pragma unroll
        for (int bt = 0; bt < 8; bt++) {
            bf16x8 af = *(const bf16x8*)&xh[(bt * 16 + lm) * pitch + k0];
            acc[bt] = __builtin_amdgcn_mfma_f32_16x16x32_bf16(af, bf, acc[bt], 0, 0, 0);
        }
    }
#pragma unroll
    for (int bt = 0; bt < 8; bt++)
#pragma unroll
        for (int r = 0; r < 4; r++) {
            int b = bt * 16 + quad * 4 + r;
            gout[(size_t)b * 768 + v] = acc[bt][r];
        }
}

// ---------- D2: chunked attention partials ----------
// Grid (NC_, B_) x 256. GRU-nl recomputed per block (cheap); block c==0 writes h_new.
__global__ __launch_bounds__(256) void k_attn(
    const float* __restrict__ gi_ws, const float* __restrict__ gh_ws,
    const float* __restrict__ b_ih, const float* __restrict__ b_hh,
    const float* __restrict__ hprev,
    const float* __restrict__ enc,
    const float* __restrict__ w_h, const float* __restrict__ w_s,
    const float* __restrict__ att_bias, const float* __restrict__ attn_v,
    float* __restrict__ out_hnew,
    float* __restrict__ sc_ws, float* __restrict__ ml_ws, float* __restrict__ ctxp_ws) {
    int c = blockIdx.x, b = blockIdx.y;
    int t = threadIdx.x;
    int wave = t >> 6, lane = t & 63;
    __shared__ float whs[H_], vs[H_], cs[H_], cmerge[H_];
    __shared__ float mred[4], lred[4];

    // GRU nonlinearity for this b (t = h index)
    {
        float ir = gi_ws[(size_t)b * 768 + t] + b_ih[t];
        float iz = gi_ws[(size_t)b * 768 + 256 + t] + b_ih[256 + t];
        float in_ = gi_ws[(size_t)b * 768 + 512 + t] + b_ih[512 + t];
        float hr = gh_ws[(size_t)b * 768 + t] + b_hh[t];
        float hz = gh_ws[(size_t)b * 768 + 256 + t] + b_hh[256 + t];
        float hn = gh_ws[(size_t)b * 768 + 512 + t] + b_hh[512 + t];
        float hp = hprev[(size_t)b * H_ + t];
        float r = sigmoid_fast(ir + hr);
        float z = sigmoid_fast(iz + hz);
        float n = tanh_fast(in_ + r * hn);
        float h = (1.0f - z) * n + z * hp;
        if (c == 0) out_hnew[(size_t)b * H_ + t] = h;
        whs[t] = w_h[t];
        vs[t] = attn_v[t];
        cs[t] = w_s[t] * h + att_bias[0];
        cmerge[t] = 0.0f;
    }
    __syncthreads();

    int h0 = lane * 4;
    // loop-invariant LDS values -> registers
    float wh0 = whs[h0], wh1 = whs[h0 + 1], wh2 = whs[h0 + 2], wh3 = whs[h0 + 3];
    float vv0 = vs[h0], vv1 = vs[h0 + 1], vv2 = vs[h0 + 2], vv3 = vs[h0 + 3];
    float cc0 = cs[h0], cc1 = cs[h0 + 1], cc2 = cs[h0 + 2], cc3 = cs[h0 + 3];

    float m_w = -1e30f, l_w = 0.0f;
    float cx0 = 0.f, cx1 = 0.f, cx2 = 0.f, cx3 = 0.f;
    for (int si = wave; si < CS_; si += 4) {
        int s = c * CS_ + si;
        float4 u = *(const float4*)(enc + ((size_t)(b * S_ + s)) * H_ + h0);
        float p = vv0 * tanh_fast(wh0 * u.x + cc0)
                + vv1 * tanh_fast(wh1 * u.y + cc1)
                + vv2 * tanh_fast(wh2 * u.z + cc2)
                + vv3 * tanh_fast(wh3 * u.w + cc3);
        p = waveReduceSumAll(p);
        if (lane == 0) sc_ws[b * S_ + s] = p;
        float mn = fmaxf(m_w, p);
        float scale = __expf(m_w - mn);
        float w = __expf(p - mn);
        cx0 = cx0 * scale + w * u.x;
        cx1 = cx1 * scale + w * u.y;
        cx2 = cx2 * scale + w * u.z;
        cx3 = cx3 * scale + w * u.w;
        l_w = l_w * scale + w;
        m_w = mn;
    }
    if (lane == 0) mred[wave] = m_w;
    __syncthreads();
    float m_c = fmaxf(fmaxf(mred[0], mred[1]), fmaxf(mred[2], mred[3]));
    float wf = __expf(m_w - m_c);
    if (lane == 0) lred[wave] = l_w * wf;
    atomicAdd(&cmerge[h0 + 0], cx0 * wf);
    atomicAdd(&cmerge[h0 + 1], cx1 * wf);
    atomicAdd(&cmerge[h0 + 2], cx2 * wf);
    atomicAdd(&cmerge[h0 + 3], cx3 * wf);
    __syncthreads();
    if (t == 0) {
        ml_ws[(b * NC_ + c) * 2 + 0] = m_c;
        ml_ws[(b * NC_ + c) * 2 + 1] = lred[0] + lred[1] + lred[2] + lred[3];
    }
    ctxp_ws[(size_t)(b * NC_ + c) * H_ + t] = cmerge[t];
}

// ---------- D3: combine chunks -> att_dist, ctx; outh GEMV (bf16 out); p_gen ----------
// Grid B_ x 1024 (16 waves).
__global__ __launch_bounds__(1024) void k_combine(
    const float* __restrict__ sc_ws, const float* __restrict__ ml_ws,
    const float* __restrict__ ctxp_ws,
    const float* __restrict__ out_hnew,
    const int* __restrict__ token, const float* __restrict__ emb,
    const float* __restrict__ outh_w, const float* __restrict__ outh_b,
    const float* __restrict__ gen_w, const float* __restrict__ gen_b,
    float* __restrict__ out_attd, float* __restrict__ out_pgen,
    ushort_t* __restrict__ hidbf_ws) {
    int b = blockIdx.x;
    int t = threadIdx.x;
    int wave = t >> 6, lane = t & 63;
    __shared__ float ml[NC_ * 2];
    __shared__ float dc[2 * H_ + E_];
    __shared__ float r2[16];

    if (t < NC_ * 2) ml[t] = ml_ws[b * NC_ * 2 + t];
    __syncthreads();
    float M = -1e30f;
#pragma unroll
    for (int c = 0; c < NC_; c++) M = fmaxf(M, ml[2 * c]);
    float L = 0.0f;
#pragma unroll
    for (int c = 0; c < NC_; c++) L += ml[2 * c + 1] * __expf(ml[2 * c] - M);
    float invL = 1.0f / L;

    if (t < S_) {
        out_attd[(size_t)b * S_ + t] = __expf(sc_ws[b * S_ + t] - M) * invL;
    }
    if (t < H_) {
        float acc = 0.0f;
#pragma unroll
        for (int c = 0; c < NC_; c++)
            acc += __expf(ml[2 * c] - M) * ctxp_ws[(size_t)(b * NC_ + c) * H_ + t];
        dc[t] = out_hnew[(size_t)b * H_ + t];
        dc[H_ + t] = acc * invL;
    }
    if (t < E_) dc[2 * H_ + t] = emb[(size_t)token[b] * E_ + t];
    __syncthreads();

    // hidden[r] = dot(outh_w[r, 0:512], dc[0:512]) + outh_b[r], 8 thr/row -> bf16
    {
        int r = t >> 3, sub = t & 7;
        const float* wrow = outh_w + (size_t)r * (2 * H_);
        float acc = 0.0f;
#pragma unroll
        for (int i = 0; i < 16; i++) {
            int k = i * 32 + sub * 4;
            float4 q = *(const float4*)(wrow + k);
            acc += dc[k] * q.x + dc[k + 1] * q.y + dc[k + 2] * q.z + dc[k + 3] * q.w;
        }
        acc += __shfl_down(acc, 4, 64);
        acc += __shfl_down(acc, 2, 64);
        acc += __shfl_down(acc, 1, 64);
        if (sub == 0) hidbf_ws[(size_t)b * E_ + r] = f2bfu(acc + outh_b[r]);
    }
    // p_gen
    float pp = (t < 2 * H_ + E_) ? dc[t] * gen_w[t] : 0.0f;
    pp = waveReduceSumAll(pp);
    if (lane == 0) r2[wave] = pp;
    __syncthreads();
    if (t == 0) {
        float g = 0.0f;
#pragma unroll
        for (int wv = 0; wv < 16; wv++) g += r2[wv];
        out_pgen[b] = sigmoid_fast(g + gen_b[0]);
    }
}

// ---------- shared staging for vocab passes: hid bf16 [B][HID_PITCH] LDS ----------
#define VT_TOTAL (V_ / 16)          // 3125
#define HID_PITCH 136               // 128+8 shorts (bank-conflict-free rows)

__device__ __forceinline__ void stage_hid(const ushort_t* __restrict__ hidbf_ws,
                                          ushort_t* __restrict__ hid, int t) {
    // hidbf_ws is B_*E_ shorts = 16384 dwords; rows are 64 dwords wide.
    const uint4* src = (const uint4*)hidbf_ws;   // 4096 uint4
#pragma unroll
    for (int i = 0; i < 16; i++) {
        int i4 = i * 256 + t;                    // uint4 index
        uint4 q = src[i4];
        int row = i4 >> 4;                       // 16 uint4 per row
        int col4 = (i4 & 15) * 4;                // dword col within row
        *(uint4*)&hid[row * HID_PITCH + col4 * 2] = q;
    }
}

__device__ __forceinline__ void vocab_gemm(const ushort_t* __restrict__ hid,
                                           const float* __restrict__ wrow,
                                           int lm, int quad, f32x4 acc[8]) {
#pragma unroll
    for (int kc = 0; kc < 4; kc++) {
        int k0 = kc * 32 + quad * 8;
        float4 w0 = *(const float4*)(wrow + k0);
        float4 w1 = *(const float4*)(wrow + k0 + 4);
        bf16x8 bf;
        bf[0] = (short)f2bfu(w0.x); bf[1] = (short)f2bfu(w0.y);
        bf[2] = (short)f2bfu(w0.z); bf[3] = (short)f2bfu(w0.w);
        bf[4] = (short)f2bfu(w1.x); bf[5] = (short)f2bfu(w1.y);
        bf[6] = (short)f2bfu(w1.z); bf[7] = (short)f2bfu(w1.w);
#pragma unroll
        for (int bt = 0; bt < 8; bt++) {
            bf16x8 af = *(const bf16x8*)&hid[(bt * 16 + lm) * HID_PITCH + k0];
            acc[bt] = __builtin_amdgcn_mfma_f32_16x16x32_bf16(af, bf, acc[bt], 0, 0, 0);
        }
    }
}

// ---------- D4: vocab GEMM -> exp -> striped row sums (no exp store) ----------
__global__ __launch_bounds__(256) void k_vocab_sum(
    const float* __restrict__ outv_w, const float* __restrict__ outv_b,
    const ushort_t* __restrict__ hidbf_ws,
    float* __restrict__ row_sum16) {
    __shared__ ushort_t hid[B_ * HID_PITCH];   // 34816 B
    __shared__ float rsum[B_];
    int t = threadIdx.x;
    stage_hid(hidbf_ws, hid, t);
    if (t < B_) rsum[t] = 0.0f;
    __syncthreads();

    int wave = t >> 6, lane = t & 63, lm = lane & 15, quad = lane >> 4;
    int vt = blockIdx.x * 4 + wave;

    if (vt < VT_TOTAL) {
        int v = vt * 16 + lm;
        const float* wrow = outv_w + (size_t)v * E_;
        f32x4 acc[8];
#pragma unroll
        for (int bt = 0; bt < 8; bt++) acc[bt] = (f32x4){0.f, 0.f, 0.f, 0.f};
        vocab_gemm(hid, wrow, lm, quad, acc);

        float bias = outv_b[v];
#pragma unroll
        for (int bt = 0; bt < 8; bt++) {
#pragma unroll
            for (int r = 0; r < 4; r++) {
                int b = bt * 16 + quad * 4 + r;
                float e = __expf(fminf(acc[bt][r] + bias, 60.0f));
                float s = e;
                s += __shfl_xor(s, 1);
                s += __shfl_xor(s, 2);
                s += __shfl_xor(s, 4);
                s += __shfl_xor(s, 8);
                if (lm == 0) atomicAdd(&rsum[b], s);
            }
        }
    }
    __syncthreads();
    if (t < B_) atomicAdd(&row_sum16[(blockIdx.x & (NSUM_ - 1)) * B_ + t], rsum[t]);
}

// ---------- D5: vocab GEMM again (L3-hit) -> write normalized p_vocab + p_final ----
__global__ __launch_bounds__(256) void k_vocab_write(
    const float* __restrict__ outv_w, const float* __restrict__ outv_b,
    const ushort_t* __restrict__ hidbf_ws,
    const float* __restrict__ row_sum16, const float* __restrict__ pgen,
    float* __restrict__ out_pvocab, float* __restrict__ out_pfinal) {
    __shared__ ushort_t hid[B_ * HID_PITCH];   // 34816 B
    __shared__ float rsinv[B_], pgs[B_];
    int t = threadIdx.x;
    stage_hid(hidbf_ws, hid, t);
    if (t < B_) {
        float rs = 0.0f;
#pragma unroll
        for (int i = 0; i < NSUM_; i++) rs += row_sum16[i * B_ + t];
        rsinv[t] = 1.0f / rs;
        pgs[t] = pgen[t];
    }
    __syncthreads();

    int wave = t >> 6, lane = t & 63, lm = lane & 15, quad = lane >> 4;
    int vt = blockIdx.x * 4 + wave;

    if (vt < VT_TOTAL) {
        int v = vt * 16 + lm;
        const float* wrow = outv_w + (size_t)v * E_;
        f32x4 acc[8];
#pragma unroll
        for (int bt = 0; bt < 8; bt++) acc[bt] = (f32x4){0.f, 0.f, 0.f, 0.f};
        vocab_gemm(hid, wrow, lm, quad, acc);

        float bias = outv_b[v];
#pragma unroll
        for (int bt = 0; bt < 8; bt++) {
#pragma unroll
            for (int r = 0; r < 4; r++) {
                int b = bt * 16 + quad * 4 + r;
                float e = __expf(fminf(acc[bt][r] + bias, 60.0f));
                float p = e * rsinv[b];
                out_pvocab[(size_t)b * V_ + v] = p;
                out_pfinal[(size_t)b * VP_ + v] = p * pgs[b];
            }
        }
    }
}

// ---------- D6: zero PAD region, then scatter atomics (block-local order) ----------
__global__ __launch_bounds__(256) void k_scatter(
    const int* __restrict__ fiv, const float* __restrict__ attd,
    const float* __restrict__ pgen, float* __restrict__ out_pfinal) {
    int b = blockIdx.x;
    int t = threadIdx.x;
    float* pfrow = out_pfinal + (size_t)b * VP_;
    if (t < PAD_) pfrow[V_ + t] = 0.0f;
    __syncthreads();   // pads (scatter may target them) written before atomics
    float omg = 1.0f - pgen[b];
    for (int s = t; s < S_; s += 256) {
        int idx = fiv[b * S_ + s];
        atomicAdd(&pfrow[idx], omg * attd[(size_t)b * S_ + s]);
    }
}

extern "C" void kernel_launch(void* const* d_in, const int* in_sizes, int n_in,
                              void* d_out, int out_size, void* d_ws, size_t ws_size,
                              hipStream_t stream) {
    const int* token = (const int*)d_in[0];
    const float* hprev = (const float*)d_in[1];
    const float* enc = (const float*)d_in[2];
    const int* fiv = (const int*)d_in[3];
    const float* emb = (const float*)d_in[4];
    const float* w_ih = (const float*)d_in[5];
    const float* w_hh = (const float*)d_in[6];
    const float* b_ih = (const float*)d_in[7];
    const float* b_hh = (const float*)d_in[8];
    const float* w_h = (const float*)d_in[9];
    const float* w_s = (const float*)d_in[10];
    const float* att_bias = (const float*)d_in[11];
    const float* attn_v = (const float*)d_in[12];
    const float* gen_w = (const float*)d_in[13];
    const float* gen_b = (const float*)d_in[14];
    const float* outh_w = (const float*)d_in[15];
    const float* outh_b = (const float*)d_in[16];
    const float* outv_w = (const float*)d_in[17];
    const float* outv_b = (const float*)d_in[18];

    float* out = (float*)d_out;
    float* out_hnew = out;                                    // B*H
    float* out_pfinal = out + (size_t)B_ * H_;                // B*VP
    float* out_pgen = out_pfinal + (size_t)B_ * VP_;          // B
    float* out_pvocab = out_pgen + B_;                        // B*V
    float* out_attd = out_pvocab + (size_t)B_ * V_;           // B*S

    float* wsf = (float*)d_ws;
    float* gi_ws = wsf;                        // 98304 floats
    float* gh_ws = wsf + 98304;                // 98304
    float* row_sum16 = wsf + 196608;           // 2048
    float* sc_ws = wsf + 198656;               // 51200
    float* ml_ws = wsf + 249856;               // 2048
    float* ctxp_ws = wsf + 251904;             // 262144
    ushort_t* hidbf_ws = (ushort_t*)(wsf + 514048);  // 16384 shorts = 8192 floats

    k_gates<<<24, 256, 0, stream>>>(token, emb, hprev, w_ih, w_hh,
                                    gi_ws, gh_ws, row_sum16);
    k_attn<<<dim3(NC_, B_), 256, 0, stream>>>(gi_ws, gh_ws, b_ih, b_hh, hprev,
                                              enc, w_h, w_s, att_bias, attn_v,
                                              out_hnew, sc_ws, ml_ws, ctxp_ws);
    k_combine<<<B_, 1024, 0, stream>>>(sc_ws, ml_ws, ctxp_ws, out_hnew, token, emb,
                                       outh_w, outh_b, gen_w, gen_b,
                                       out_attd, out_pgen, hidbf_ws);
    k_vocab_sum<<<782, 256, 0, stream>>>(outv_w, outv_b, hidbf_ws, row_sum16);
    k_vocab_write<<<782, 256, 0, stream>>>(outv_w, outv_b, hidbf_ws,
                                           row_sum16, out_pgen,
                                           out_pvocab, out_pfinal);
    k_scatter<<<B_, 256, 0, stream>>>(fiv, out_attd, out_pgen, out_pfinal);
}